// Round 3
// baseline (294.121 us; speedup 1.0000x reference)
//
#include <hip/hip_runtime.h>

// Problem: B=64, T=512, C_IN=128, C_OUT=16
// out[bt, i*C_OUT + j] = x[bt, i] * W[i, j] + b[i, j]
// x: [B*T, C_IN] f32 (16 MiB), W,b: [C_IN, C_OUT] f32 (8 KiB each),
// out: [B*T, C_IN*C_OUT] f32 (256 MiB). Pure HBM-write-bound broadcast FMA.
// Roofline: ~272 MiB / 6.3 TB/s ≈ 45 us (harness poison/restore adds fixed
// ~235 us to dur_us per round-2 evidence: kernel absent from top-5 while
// 1 GiB fills at 170 us dominate).

constexpr int kB = 64;
constexpr int kT = 512;
constexpr int kCIn = 128;
constexpr int kCOut = 16;
constexpr int kRow4 = (kCIn * kCOut) / 4;       // 512 float4 per bt row
constexpr int kN4 = kB * kT * kRow4;            // 16,777,216 float4 outputs

constexpr int kBlock = 256;
constexpr int kGrid = 2048;                     // 8 blocks/CU on 256 CUs
constexpr int kStride = kBlock * kGrid;         // 524288 (multiple of 512)
constexpr int kIters = kN4 / kStride;           // exactly 32, no remainder
static_assert(kIters * kStride == kN4, "exact tiling");
constexpr int kBtStride = kStride / kRow4;      // 1024 rows per iteration

__global__ __launch_bounds__(kBlock) void realemb_kernel(
    const float* __restrict__ x,
    const float4* __restrict__ W4,   // W viewed as [C_IN*C_OUT/4] float4
    const float4* __restrict__ b4,
    float4* __restrict__ out4)
{
    const int idx = blockIdx.x * kBlock + threadIdx.x;

    const int c4 = idx & (kRow4 - 1);            // loop-invariant float4 col
    const int i = c4 >> 2;                       // input feature index
    const float4 w = W4[c4];
    const float4 bb = b4[c4];

    const int bt0 = idx >> 9;                    // starting bt row
    const float* __restrict__ xp = x + (size_t)bt0 * kCIn + i;
    float4* __restrict__ op = out4 + idx;

    // Fixed trip count -> full unroll: 32 independent x loads pipelined
    // ahead of 32 unit-stride dwordx4 stores (1 KiB per wave instruction).
    #pragma unroll
    for (int it = 0; it < kIters; ++it) {
        float xv = xp[(size_t)it * kBtStride * kCIn];
        float4 o;
        o.x = fmaf(xv, w.x, bb.x);
        o.y = fmaf(xv, w.y, bb.y);
        o.z = fmaf(xv, w.z, bb.z);
        o.w = fmaf(xv, w.w, bb.w);
        op[(size_t)it * kStride] = o;
    }
}

extern "C" void kernel_launch(void* const* d_in, const int* in_sizes, int n_in,
                              void* d_out, int out_size, void* d_ws, size_t ws_size,
                              hipStream_t stream) {
    const float* x = (const float*)d_in[0];
    const float4* W4 = (const float4*)d_in[1];
    const float4* b4 = (const float4*)d_in[2];
    float4* out4 = (float4*)d_out;

    realemb_kernel<<<kGrid, kBlock, 0, stream>>>(x, W4, b4, out4);
}